// Round 2
// baseline (324.835 us; speedup 1.0000x reference)
//
#include <hip/hip_runtime.h>
#include <math.h>

typedef __attribute__((ext_vector_type(8))) short short8;
typedef __attribute__((ext_vector_type(8))) _Float16 half8;
typedef __attribute__((ext_vector_type(4))) _Float16 half4;
typedef __attribute__((ext_vector_type(2))) _Float16 half2;
typedef __attribute__((ext_vector_type(4))) float floatx4;
typedef __attribute__((ext_vector_type(4))) unsigned int uintx4;

#define NB    4
#define CIN   64
#define COUT  128
#define IMH   128
#define IMW   256
#define KTOT  576
#define NPIX  (IMH * IMW)
#define PXT   128
#define NDPB  (PXT * 9)        // 1152 descriptors (px x tap)
#define ROWS  4                // staged rows r-2..r+1 (|new_r - r| < 1.415 proven)
#define CSTW  6                // u32 words per staged col (4 data f16x8 + 2 pad)
#define NCOL  257              // cols 0..255 + zero col 256
#define RSTW  (NCOL * CSTW)    // 1542 u32 words per staged row
#define SLSTR 104              // u16 per px in Sl (96 K + 8 pad)
#define KCH   96               // padded K per chunk (72 real + 24 zeros)

__device__ __forceinline__ unsigned pkrtz2(float a, float b) {
  unsigned r;
  asm("v_cvt_pkrtz_f16_f32 %0, %1, %2" : "=v"(r) : "v"(a), "v"(b));
  return r;
}
__device__ __forceinline__ half4 dup4(unsigned u) {
  half2 h; __builtin_memcpy(&h, &u, 4);
  return __builtin_shufflevector(h, h, 0, 1, 0, 1);
}

// ---- kernel 1: weight fp32 [co][ci*9+t] -> f16, K' = chunk*96 + t*8 + (ci&7) ----
__global__ __launch_bounds__(256) void prep_w_kernel(const float* __restrict__ w,
                                                     unsigned short* __restrict__ wbf) {
  int idx = blockIdx.x * 256 + threadIdx.x;
  if (idx >= COUT * 8 * KCH) return;
  int co = idx / (8 * KCH);
  int K2 = idx - co * (8 * KCH);
  int cb = K2 / KCH, kk = K2 - cb * KCH;
  unsigned short v = 0;
  if (kk < 72) {
    int t = kk >> 3, chl = kk & 7;
    int ci = cb * 8 + chl;
    _Float16 h = (_Float16)w[co * KTOT + ci * 9 + t];
    __builtin_memcpy(&v, &h, 2);
  }
  wbf[(K2 >> 3) * (COUT * 8) + co * 8 + (K2 & 7)] = v;
}

// ---- kernel 2: tap-hoisted desc-gen + f16 staging + pk_fma gather + f16 MFMA ----
__global__ __launch_bounds__(512, 6) void sphconv_kernel(
    const float* __restrict__ x, const unsigned short* __restrict__ wbf,
    const float* __restrict__ bias, float* __restrict__ out) {
  __shared__ __align__(16) unsigned int stg[ROWS * RSTW];     // 24,672 B (f16 pairs)
  __shared__ __align__(16) unsigned short Sl[PXT * SLSTR];    // 26,624 B
  __shared__ double tapA[9];       // atan-term (col-independent)
  __shared__ float  tapWy[9][2];   // wy0m, wy1m
  __shared__ int    tapRo[9][2];   // rt*RSTW, rb*RSTW

  const int tid  = threadIdx.x;
  const int lane = tid & 63;
  const int wv   = tid >> 6;
  // XCD-chunked swizzle (bijective, 256 = 8*32)
  const int lin = blockIdx.x + 2 * blockIdx.y;
  const int sw  = (lin & 7) * 32 + (lin >> 3);
  const int ct  = sw >> 7;
  const int r   = sw & 127;
  const int n   = blockIdx.z;
  const int c0  = ct * PXT;
  const int co_base = (wv & 1) * 64;
  const int px_base = (wv >> 1) * 32;
  const int rlo  = min(max(r - 2, 0), IMH - ROWS);
  // staging roles: ch-pair x col-group x row-pair
  const int sp  = tid & 3;
  const int scg = (tid >> 2) & 63;
  const int srr = tid >> 8;

  const float* xn = x + (size_t)n * CIN * NPIX;

  // ---- prologue: issue chunk-0 staging loads (land during tap/desc gen) ----
  floatx4 nx[4];
  #pragma unroll
  for (int c = 0; c < 2; c++)
    #pragma unroll
    for (int rw = 0; rw < 2; rw++)
      nx[c * 2 + rw] = *(const floatx4*)(xn + (size_t)(sp * 2 + c) * NPIX
                                         + (size_t)(rlo + srr * 2 + rw) * IMW + scg * 4);

  // ---- phase 0a: per-tap f64 transcendentals (9 designated lanes only) ----
  {
    int myk = -1;
    if (lane == 0) myk = wv;
    if (wv == 0 && lane == 32) myk = 8;
    if (myk >= 0) {
      const double pi = 3.14159265358979323846;
      double dphi = pi / IMH;
      double dth  = 2.0 * pi / IMW;
      double t  = tan(dth);
      double p  = tan(dphi);
      double sp_ = p / cos(dth);
      double phi  = -(((double)r + 0.5) / IMH * pi - pi * 0.5);
      double sphi = sin(phi), cphi = cos(phi);
      int i = myk / 3, j = myk % 3;
      double atv, new_r;
      if (myk == 4) {
        atv = 0.0; new_r = (double)r;
      } else {
        double X = (j == 0) ? -t : ((j == 2) ? t : 0.0);
        double Y = 0.0;
        if (i == 0)      Y = (j == 1) ?  p :  sp_;
        else if (i == 2) Y = (j == 1) ? -p : -sp_;
        double rho = sqrt(X * X + Y * Y);
        double v   = atan(rho);
        double sv = sin(v), cv = cos(v);
        double arg = cv * sphi + Y * sv * cphi / rho;
        arg = fmin(1.0, fmax(-1.0, arg));
        double new_phi = asin(arg);
        double denom = rho * cphi * cv - Y * sphi * sv;
        atv = atan(X * sv / denom);
        new_r = (-new_phi + pi * 0.5) * IMH / pi - 0.5;
      }
      // y-side products (col-independent)
      float gy = (float)(new_r * 2.0 / IMH - 1.0);
      float iy = ((gy + 1.0f) * (float)IMH - 1.0f) * 0.5f;
      float fy = floorf(iy); int y0 = (int)fy;
      float wy1 = iy - fy, wy0 = 1.0f - wy1;
      int y1 = y0 + 1;
      bool vy0 = (y0 >= 0) & (y0 <= IMH - 1);
      bool vy1 = (y1 >= 0) & (y1 <= IMH - 1);
      int y0c = min(max(y0, 0), IMH - 1), y1c = min(max(y1, 0), IMH - 1);
      int rt = min(max(y0c - rlo, 0), ROWS - 1);
      int rb = min(max(y1c - rlo, 0), ROWS - 1);
      tapA[myk] = atv;
      tapWy[myk][0] = vy0 ? wy0 : 0.0f;
      tapWy[myk][1] = vy1 ? wy1 : 0.0f;
      tapRo[myk][0] = rt * RSTW;
      tapRo[myk][1] = rb * RSTW;
    }
  }
  __syncthreads();   // taps visible

  // ---- phase 0b: per-descriptor x-side (cheap; 4 f64 ops + f32) ----
  int opk[3] = {0, 0, 0}, slw[3] = {0, 0, 0};
  unsigned uq0[3] = {0,0,0}, uq1[3] = {0,0,0}, uq2[3] = {0,0,0}, uq3[3] = {0,0,0};
  {
    const double pi = 3.14159265358979323846;
    #pragma unroll
    for (int dd = 0; dd < 3; dd++) {
      if (dd < 2 || tid < NDPB - 1024) {
        int d  = tid + dd * 512;
        int px = d & (PXT - 1), k = d >> 7;
        int c  = c0 + px;
        double nc;
        if (k == 4) {
          nc = (double)c;
        } else {
          double theta = ((double)c + 0.5) / IMW * (2.0 * pi) - pi;
          double new_theta = theta + tapA[k];
          nc = (new_theta + pi) * IMW / (2.0 * pi) - 0.5;
          nc = fmod(nc + (double)IMW, (double)IMW);
        }
        float gx = (float)(nc * 2.0 / IMW - 1.0);
        float ix = ((gx + 1.0f) * (float)IMW - 1.0f) * 0.5f;
        float fx = floorf(ix); int x0 = (int)fx;
        float wx1 = ix - fx, wx0 = 1.0f - wx1;
        int x1 = x0 + 1;
        int x0c = max(x0, 0);
        float w_lo = (x0 >= 0) ? wx0 : wx1;
        float w_hi = (x0 >= 0) ? ((x1 <= IMW - 1) ? wx1 : 0.0f) : 0.0f;
        float wy0m = tapWy[k][0], wy1m = tapWy[k][1];
        float w0 = wy0m * w_lo, w1 = wy0m * w_hi;
        float w2 = wy1m * w_lo, w3 = wy1m * w_hi;
        int sh0 = ((x0c >> 4) & 1) * 2;
        int sh1 = (((x0c + 1) >> 4) & 1) * 2;
        int dc  = CSTW + sh1 - sh0;
        int offt = tapRo[k][0] + x0c * CSTW + sh0;   // <= 6164, fits 16b
        int offb = tapRo[k][1] + x0c * CSTW + sh0;
        opk[dd] = offt | (offb << 16);
        slw[dd] = (px * (SLSTR / 2) + k * 4) | (dc << 16);
        uq0[dd] = pkrtz2(w0, w0); uq1[dd] = pkrtz2(w1, w1);
        uq2[dd] = pkrtz2(w2, w2); uq3[dd] = pkrtz2(w3, w3);
      }
    }
  }

  // ---- write chunk-0 stage (f16 pairs, sh-swizzled: 2-way max) + zeros ----
  #pragma unroll
  for (int rw = 0; rw < 2; rw++)
    #pragma unroll
    for (int i = 0; i < 4; i++) {
      int col = scg * 4 + i;
      int sh = ((col >> 4) & 1) * 2;
      stg[(srr * 2 + rw) * RSTW + col * CSTW + sh + sp] =
          pkrtz2(nx[rw][i], nx[2 + rw][i]);
    }
  if (tid < 16) stg[(tid >> 2) * RSTW + 256 * CSTW + (tid & 3)] = 0u;
  #pragma unroll
  for (int z = 0; z < 3; z++) {                 // Sl K-pad (taps 9-11): stays zero
    int q = tid + z * 512;
    int px = q / 12;
    ((unsigned int*)Sl)[px * 52 + 36 + (q - px * 12)] = 0u;
  }

  floatx4 acc[4][2];
  #pragma unroll
  for (int mt = 0; mt < 4; mt++)
    #pragma unroll
    for (int nt = 0; nt < 2; nt++)
      acc[mt][nt] = (floatx4){0.f, 0.f, 0.f, 0.f};

  __syncthreads();   // stg + zeros ready

  #pragma unroll 1
  for (int cb = 0; cb < 8; cb++) {
    // ---- issue next chunk's global loads EARLY (hide under gather) ----
    if (cb < 7) {
      #pragma unroll
      for (int c = 0; c < 2; c++)
        #pragma unroll
        for (int rw = 0; rw < 2; rw++)
          nx[c * 2 + rw] = *(const floatx4*)(xn + (size_t)((cb + 1) * 8 + sp * 2 + c) * NPIX
                                             + (size_t)(rlo + srr * 2 + rw) * IMW + scg * 4);
    }
    // ---- gather: 8 x ds_read_b64 + pk_fma_f16 + 1 x ds_write_b128 per desc ----
    #pragma unroll
    for (int dd = 0; dd < 3; dd++) {
      if (dd < 2 || tid < NDPB - 1024) {
        unsigned op = (unsigned)opk[dd];
        const unsigned* pt = stg + (op & 0xFFFFu);
        const unsigned* pb = stg + (op >> 16);
        int dc = slw[dd] >> 16;
        half4 t0  = *(const half4*)(pt);
        half4 t0h = *(const half4*)(pt + 2);
        half4 t1  = *(const half4*)(pt + dc);
        half4 t1h = *(const half4*)(pt + dc + 2);
        half4 b0  = *(const half4*)(pb);
        half4 b0h = *(const half4*)(pb + 2);
        half4 b1  = *(const half4*)(pb + dc);
        half4 b1h = *(const half4*)(pb + dc + 2);
        half4 W0 = dup4(uq0[dd]), W1 = dup4(uq1[dd]);
        half4 W2 = dup4(uq2[dd]), W3 = dup4(uq3[dd]);
        half4 slo = t0 * W0 + t1 * W1 + b0 * W2 + b1 * W3;
        half4 shi = t0h * W0 + t1h * W1 + b0h * W2 + b1h * W3;
        union { half4 h; unsigned u[2]; } ua, ub;
        ua.h = slo; ub.h = shi;
        uintx4 U = {ua.u[0], ua.u[1], ub.u[0], ub.u[1]};
        *(uintx4*)((unsigned int*)Sl + (slw[dd] & 0xFFFF)) = U;
      }
    }
    __syncthreads();            // Sl ready; stg reads done
    // ---- write next chunk's stage (loads landed during gather) ----
    if (cb < 7) {
      #pragma unroll
      for (int rw = 0; rw < 2; rw++)
        #pragma unroll
        for (int i = 0; i < 4; i++) {
          int col = scg * 4 + i;
          int sh = ((col >> 4) & 1) * 2;
          stg[(srr * 2 + rw) * RSTW + col * CSTW + sh + sp] =
              pkrtz2(nx[rw][i], nx[2 + rw][i]);
        }
    }
    // ---- MFMA: 3 x K32 steps (f16) ----
    __builtin_amdgcn_s_setprio(1);
    #pragma unroll
    for (int ks = 0; ks < 3; ks++) {
      const unsigned short* arow =
          wbf + (size_t)((cb * 12 + ks * 4 + (lane >> 4)) * COUT + co_base + (lane & 15)) * 8;
      #pragma unroll
      for (int nt = 0; nt < 2; nt++) {
        half8 b = *(const half8*)&Sl[(px_base + nt * 16 + (lane & 15)) * SLSTR
                                     + ks * 32 + (lane >> 4) * 8];
        #pragma unroll
        for (int mt = 0; mt < 4; mt++) {
          half8 a = *(const half8*)(arow + mt * 16 * 8);
          acc[mt][nt] = __builtin_amdgcn_mfma_f32_16x16x32_f16(a, b, acc[mt][nt], 0, 0, 0);
        }
      }
    }
    __builtin_amdgcn_s_setprio(0);
    __syncthreads();            // Sl free; stg(cb+1) ready
  }

  // ---- epilogue: D row = co, col = px ----
  #pragma unroll
  for (int mt = 0; mt < 4; mt++)
    #pragma unroll
    for (int nt = 0; nt < 2; nt++)
      #pragma unroll
      for (int rg = 0; rg < 4; rg++) {
        const int co = co_base + mt * 16 + (lane >> 4) * 4 + rg;
        const int cc = c0 + px_base + nt * 16 + (lane & 15);
        out[(((size_t)n * COUT + co) * IMH + r) * IMW + cc] = acc[mt][nt][rg] + bias[co];
      }
}

extern "C" void kernel_launch(void* const* d_in, const int* in_sizes, int n_in,
                              void* d_out, int out_size, void* d_ws, size_t ws_size,
                              hipStream_t stream) {
  const float* x    = (const float*)d_in[0];
  const float* w    = (const float*)d_in[1];
  const float* bias = (const float*)d_in[2];
  float* out = (float*)d_out;
  unsigned short* wbf = (unsigned short*)d_ws;   // 192 KB workspace
  (void)in_sizes; (void)n_in; (void)out_size; (void)ws_size;

  hipLaunchKernelGGL(prep_w_kernel, dim3((COUT * 8 * KCH + 255) / 256), dim3(256), 0, stream, w, wbf);
  hipLaunchKernelGGL(sphconv_kernel, dim3(IMW / PXT, IMH, NB), dim3(512), 0, stream,
                     x, wbf, bias, out);
}

// Round 4
// 146.037 us; speedup vs baseline: 2.2243x; 2.2243x over previous
//
#include <hip/hip_runtime.h>
#include <math.h>

typedef __attribute__((ext_vector_type(8))) short short8;
typedef __attribute__((ext_vector_type(8))) _Float16 half8;
typedef __attribute__((ext_vector_type(4))) _Float16 half4;
typedef __attribute__((ext_vector_type(2))) _Float16 half2;
typedef __attribute__((ext_vector_type(4))) float floatx4;
typedef __attribute__((ext_vector_type(4))) unsigned int uintx4;

#define NB    4
#define CIN   64
#define COUT  128
#define IMH   128
#define IMW   256
#define KTOT  576
#define NPIX  (IMH * IMW)
#define PXT   128
#define NDPB  (PXT * 9)        // 1152 descriptors (px x tap)
#define ROWS  4                // staged rows r-2..r+1 (|new_r - r| < 1.415 proven)
#define CSTW  6                // u32 words per staged col (4 data f16x8 + 2 pad)
#define NCOL  257              // cols 0..255 + zero col 256
#define RSTW  (NCOL * CSTW)    // 1542 u32 words per staged row
#define SLSTR 104              // u16 per px in Sl (96 K + 8 pad)
#define KCH   96               // padded K per chunk (72 real + 24 zeros)

__device__ __forceinline__ unsigned pkrtz2(float a, float b) {
  unsigned r;
  asm("v_cvt_pkrtz_f16_f32 %0, %1, %2" : "=v"(r) : "v"(a), "v"(b));
  return r;
}
__device__ __forceinline__ half4 dup4(unsigned u) {
  half2 h; __builtin_memcpy(&h, &u, 4);
  return __builtin_shufflevector(h, h, 0, 1, 0, 1);
}

// ---- kernel 1: weight fp32 [co][ci*9+t] -> f16, K' = chunk*96 + t*8 + (ci&7) ----
__global__ __launch_bounds__(256) void prep_w_kernel(const float* __restrict__ w,
                                                     unsigned short* __restrict__ wbf) {
  int idx = blockIdx.x * 256 + threadIdx.x;
  if (idx >= COUT * 8 * KCH) return;
  int co = idx / (8 * KCH);
  int K2 = idx - co * (8 * KCH);
  int cb = K2 / KCH, kk = K2 - cb * KCH;
  unsigned short v = 0;
  if (kk < 72) {
    int t = kk >> 3, chl = kk & 7;
    int ci = cb * 8 + chl;
    _Float16 h = (_Float16)w[co * KTOT + ci * 9 + t];
    __builtin_memcpy(&v, &h, 2);
  }
  wbf[(K2 >> 3) * (COUT * 8) + co * 8 + (K2 & 7)] = v;
}

// ---- kernel 2: tap-hoisted desc-gen + f16 staging + pk_fma gather + f16 MFMA ----
// (512,4): 128-reg/lane cap -> no spill (R2's (512,6) forced ~80 incl. AGPRs ->
//  massive scratch spill, 2.5x regression). 2 blocks/CU.
__global__ __launch_bounds__(512, 4) void sphconv_kernel(
    const float* __restrict__ x, const unsigned short* __restrict__ wbf,
    const float* __restrict__ bias, float* __restrict__ out) {
  __shared__ __align__(16) unsigned int stg[ROWS * RSTW];     // 24,672 B (f16 pairs)
  __shared__ __align__(16) unsigned short Sl[PXT * SLSTR];    // 26,624 B
  __shared__ double tapA[9];       // atan-term (col-independent)
  __shared__ float  tapWy[9][2];   // wy0m, wy1m
  __shared__ int    tapRo[9][2];   // rt*RSTW, rb*RSTW

  const int tid  = threadIdx.x;
  const int lane = tid & 63;
  const int wv   = tid >> 6;
  // XCD-chunked swizzle (bijective, 256 = 8*32)
  const int lin = blockIdx.x + 2 * blockIdx.y;
  const int sw  = (lin & 7) * 32 + (lin >> 3);
  const int ct  = sw >> 7;
  const int r   = sw & 127;
  const int n   = blockIdx.z;
  const int c0  = ct * PXT;
  const int co_base = (wv & 1) * 64;
  const int px_base = (wv >> 1) * 32;
  const int rlo  = min(max(r - 2, 0), IMH - ROWS);
  // staging roles: ch-pair x col-group x row-pair
  const int sp  = tid & 3;
  const int scg = (tid >> 2) & 63;
  const int srr = tid >> 8;

  const float* xn = x + (size_t)n * CIN * NPIX;

  // ---- prologue: issue chunk-0 staging loads (land during tap/desc gen) ----
  floatx4 nx[4];
  #pragma unroll
  for (int c = 0; c < 2; c++)
    #pragma unroll
    for (int rw = 0; rw < 2; rw++)
      nx[c * 2 + rw] = *(const floatx4*)(xn + (size_t)(sp * 2 + c) * NPIX
                                         + (size_t)(rlo + srr * 2 + rw) * IMW + scg * 4);

  // ---- phase 0a: per-tap f64 transcendentals (9 designated lanes only) ----
  {
    int myk = -1;
    if (lane == 0) myk = wv;
    if (wv == 0 && lane == 32) myk = 8;
    if (myk >= 0) {
      const double pi = 3.14159265358979323846;
      double dphi = pi / IMH;
      double dth  = 2.0 * pi / IMW;
      double t  = tan(dth);
      double p  = tan(dphi);
      double sp_ = p / cos(dth);
      double phi  = -(((double)r + 0.5) / IMH * pi - pi * 0.5);
      double sphi = sin(phi), cphi = cos(phi);
      int i = myk / 3, j = myk % 3;
      double atv, new_r;
      if (myk == 4) {
        atv = 0.0; new_r = (double)r;
      } else {
        double X = (j == 0) ? -t : ((j == 2) ? t : 0.0);
        double Y = 0.0;
        if (i == 0)      Y = (j == 1) ?  p :  sp_;
        else if (i == 2) Y = (j == 1) ? -p : -sp_;
        double rho = sqrt(X * X + Y * Y);
        double v   = atan(rho);
        double sv = sin(v), cv = cos(v);
        double arg = cv * sphi + Y * sv * cphi / rho;
        arg = fmin(1.0, fmax(-1.0, arg));
        double new_phi = asin(arg);
        double denom = rho * cphi * cv - Y * sphi * sv;
        atv = atan(X * sv / denom);
        new_r = (-new_phi + pi * 0.5) * IMH / pi - 0.5;
      }
      // y-side products (col-independent)
      float gy = (float)(new_r * 2.0 / IMH - 1.0);
      float iy = ((gy + 1.0f) * (float)IMH - 1.0f) * 0.5f;
      float fy = floorf(iy); int y0 = (int)fy;
      float wy1 = iy - fy, wy0 = 1.0f - wy1;
      int y1 = y0 + 1;
      bool vy0 = (y0 >= 0) & (y0 <= IMH - 1);
      bool vy1 = (y1 >= 0) & (y1 <= IMH - 1);
      int y0c = min(max(y0, 0), IMH - 1), y1c = min(max(y1, 0), IMH - 1);
      int rt = min(max(y0c - rlo, 0), ROWS - 1);
      int rb = min(max(y1c - rlo, 0), ROWS - 1);
      tapA[myk] = atv;
      tapWy[myk][0] = vy0 ? wy0 : 0.0f;
      tapWy[myk][1] = vy1 ? wy1 : 0.0f;
      tapRo[myk][0] = rt * RSTW;
      tapRo[myk][1] = rb * RSTW;
    }
  }
  __syncthreads();   // taps visible

  // ---- phase 0b: per-descriptor x-side (cheap; 4 f64 ops + f32) ----
  int opk[3] = {0, 0, 0}, slw[3] = {0, 0, 0};
  unsigned uq0[3] = {0,0,0}, uq1[3] = {0,0,0}, uq2[3] = {0,0,0}, uq3[3] = {0,0,0};
  {
    const double pi = 3.14159265358979323846;
    #pragma unroll
    for (int dd = 0; dd < 3; dd++) {
      if (dd < 2 || tid < NDPB - 1024) {
        int d  = tid + dd * 512;
        int px = d & (PXT - 1), k = d >> 7;
        int c  = c0 + px;
        double nc;
        if (k == 4) {
          nc = (double)c;
        } else {
          double theta = ((double)c + 0.5) / IMW * (2.0 * pi) - pi;
          double new_theta = theta + tapA[k];
          nc = (new_theta + pi) * IMW / (2.0 * pi) - 0.5;
          nc = fmod(nc + (double)IMW, (double)IMW);
        }
        float gx = (float)(nc * 2.0 / IMW - 1.0);
        float ix = ((gx + 1.0f) * (float)IMW - 1.0f) * 0.5f;
        float fx = floorf(ix); int x0 = (int)fx;
        float wx1 = ix - fx, wx0 = 1.0f - wx1;
        int x1 = x0 + 1;
        int x0c = max(x0, 0);
        float w_lo = (x0 >= 0) ? wx0 : wx1;
        float w_hi = (x0 >= 0) ? ((x1 <= IMW - 1) ? wx1 : 0.0f) : 0.0f;
        float wy0m = tapWy[k][0], wy1m = tapWy[k][1];
        float w0 = wy0m * w_lo, w1 = wy0m * w_hi;
        float w2 = wy1m * w_lo, w3 = wy1m * w_hi;
        int sh0 = ((x0c >> 4) & 1) * 2;
        int sh1 = (((x0c + 1) >> 4) & 1) * 2;
        int dc  = CSTW + sh1 - sh0;
        int offt = tapRo[k][0] + x0c * CSTW + sh0;   // <= 6164, fits 16b
        int offb = tapRo[k][1] + x0c * CSTW + sh0;
        opk[dd] = offt | (offb << 16);
        slw[dd] = (px * (SLSTR / 2) + k * 4) | (dc << 16);
        uq0[dd] = pkrtz2(w0, w0); uq1[dd] = pkrtz2(w1, w1);
        uq2[dd] = pkrtz2(w2, w2); uq3[dd] = pkrtz2(w3, w3);
      }
    }
  }

  // ---- write chunk-0 stage (f16 pairs, sh-swizzled) + zeros ----
  #pragma unroll
  for (int rw = 0; rw < 2; rw++)
    #pragma unroll
    for (int i = 0; i < 4; i++) {
      int col = scg * 4 + i;
      int sh = ((col >> 4) & 1) * 2;
      stg[(srr * 2 + rw) * RSTW + col * CSTW + sh + sp] =
          pkrtz2(nx[rw][i], nx[2 + rw][i]);
    }
  if (tid < 16) stg[(tid >> 2) * RSTW + 256 * CSTW + (tid & 3)] = 0u;
  #pragma unroll
  for (int z = 0; z < 3; z++) {                 // Sl K-pad (taps 9-11): stays zero
    int q = tid + z * 512;
    int px = q / 12;
    ((unsigned int*)Sl)[px * 52 + 36 + (q - px * 12)] = 0u;
  }

  floatx4 acc[4][2];
  #pragma unroll
  for (int mt = 0; mt < 4; mt++)
    #pragma unroll
    for (int nt = 0; nt < 2; nt++)
      acc[mt][nt] = (floatx4){0.f, 0.f, 0.f, 0.f};

  __syncthreads();   // stg + zeros ready

  #pragma unroll 1
  for (int cb = 0; cb < 8; cb++) {
    // ---- issue next chunk's global loads EARLY (hide under gather) ----
    if (cb < 7) {
      #pragma unroll
      for (int c = 0; c < 2; c++)
        #pragma unroll
        for (int rw = 0; rw < 2; rw++)
          nx[c * 2 + rw] = *(const floatx4*)(xn + (size_t)((cb + 1) * 8 + sp * 2 + c) * NPIX
                                             + (size_t)(rlo + srr * 2 + rw) * IMW + scg * 4);
    }
    // ---- gather: 8 x ds_read_b64 + pk_fma_f16 + 1 x ds_write_b128 per desc ----
    #pragma unroll
    for (int dd = 0; dd < 3; dd++) {
      if (dd < 2 || tid < NDPB - 1024) {
        unsigned op = (unsigned)opk[dd];
        const unsigned* pt = stg + (op & 0xFFFFu);
        const unsigned* pb = stg + (op >> 16);
        int dc = slw[dd] >> 16;
        half4 t0  = *(const half4*)(pt);
        half4 t0h = *(const half4*)(pt + 2);
        half4 t1  = *(const half4*)(pt + dc);
        half4 t1h = *(const half4*)(pt + dc + 2);
        half4 b0  = *(const half4*)(pb);
        half4 b0h = *(const half4*)(pb + 2);
        half4 b1  = *(const half4*)(pb + dc);
        half4 b1h = *(const half4*)(pb + dc + 2);
        half4 W0 = dup4(uq0[dd]), W1 = dup4(uq1[dd]);
        half4 W2 = dup4(uq2[dd]), W3 = dup4(uq3[dd]);
        half4 slo = t0 * W0 + t1 * W1 + b0 * W2 + b1 * W3;
        half4 shi = t0h * W0 + t1h * W1 + b0h * W2 + b1h * W3;
        union { half4 h; unsigned u[2]; } ua, ub;
        ua.h = slo; ub.h = shi;
        uintx4 U = {ua.u[0], ua.u[1], ub.u[0], ub.u[1]};
        *(uintx4*)((unsigned int*)Sl + (slw[dd] & 0xFFFF)) = U;
      }
    }
    __syncthreads();            // Sl ready; stg reads done
    // ---- write next chunk's stage (loads landed during gather) ----
    if (cb < 7) {
      #pragma unroll
      for (int rw = 0; rw < 2; rw++)
        #pragma unroll
        for (int i = 0; i < 4; i++) {
          int col = scg * 4 + i;
          int sh = ((col >> 4) & 1) * 2;
          stg[(srr * 2 + rw) * RSTW + col * CSTW + sh + sp] =
              pkrtz2(nx[rw][i], nx[2 + rw][i]);
        }
    }
    // ---- MFMA: 3 x K32 steps (f16) ----
    __builtin_amdgcn_s_setprio(1);
    #pragma unroll
    for (int ks = 0; ks < 3; ks++) {
      const unsigned short* arow =
          wbf + (size_t)((cb * 12 + ks * 4 + (lane >> 4)) * COUT + co_base + (lane & 15)) * 8;
      #pragma unroll
      for (int nt = 0; nt < 2; nt++) {
        half8 b = *(const half8*)&Sl[(px_base + nt * 16 + (lane & 15)) * SLSTR
                                     + ks * 32 + (lane >> 4) * 8];
        #pragma unroll
        for (int mt = 0; mt < 4; mt++) {
          half8 a = *(const half8*)(arow + mt * 16 * 8);
          acc[mt][nt] = __builtin_amdgcn_mfma_f32_16x16x32_f16(a, b, acc[mt][nt], 0, 0, 0);
        }
      }
    }
    __builtin_amdgcn_s_setprio(0);
    __syncthreads();            // Sl free; stg(cb+1) ready
  }

  // ---- epilogue: D row = co, col = px ----
  #pragma unroll
  for (int mt = 0; mt < 4; mt++)
    #pragma unroll
    for (int nt = 0; nt < 2; nt++)
      #pragma unroll
      for (int rg = 0; rg < 4; rg++) {
        const int co = co_base + mt * 16 + (lane >> 4) * 4 + rg;
        const int cc = c0 + px_base + nt * 16 + (lane & 15);
        out[(((size_t)n * COUT + co) * IMH + r) * IMW + cc] = acc[mt][nt][rg] + bias[co];
      }
}

extern "C" void kernel_launch(void* const* d_in, const int* in_sizes, int n_in,
                              void* d_out, int out_size, void* d_ws, size_t ws_size,
                              hipStream_t stream) {
  const float* x    = (const float*)d_in[0];
  const float* w    = (const float*)d_in[1];
  const float* bias = (const float*)d_in[2];
  float* out = (float*)d_out;
  unsigned short* wbf = (unsigned short*)d_ws;   // 192 KB workspace
  (void)in_sizes; (void)n_in; (void)out_size; (void)ws_size;

  hipLaunchKernelGGL(prep_w_kernel, dim3((COUT * 8 * KCH + 255) / 256), dim3(256), 0, stream, w, wbf);
  hipLaunchKernelGGL(sphconv_kernel, dim3(IMW / PXT, IMH, NB), dim3(512), 0, stream,
                     x, wbf, bias, out);
}